// Round 1
// baseline (18411.938 us; speedup 1.0000x reference)
//
#include <hip/hip_runtime.h>
#include <hip/hip_bf16.h>
#include <cstdio>
#include <cstddef>

// Problem dims
#define B_ 1024
#define S_ 50
#define H_ 256
#define T_ 512
#define D_ 512
#define DFF_ 2048
#define BS_ 51200      // B_*S_
#define BT_ 524288     // B_*T_

enum { GF_RELU = 1, GF_ADD = 2, GF_KVH = 4 };

__device__ __forceinline__ float sigmoidf_(float v) {
  return 1.f / (1.f + __expf(-v));
}

// ---------------------------------------------------------------- add pos emb
__global__ __launch_bounds__(256) void add_pos(const float* __restrict__ syl,
                                               const float* __restrict__ pos,
                                               float* __restrict__ x) {
  int idx = blockIdx.x * 256 + threadIdx.x;          // float4 index
  if (idx * 4 >= BS_ * H_) return;
  float4 s = ((const float4*)syl)[idx];
  int e0 = idx * 4;
  int h = e0 & 255;
  int sp = (e0 >> 8) % S_;
  float4 p = *(const float4*)&pos[sp * H_ + h];
  float4 o; o.x = s.x + p.x; o.y = s.y + p.y; o.z = s.z + p.z; o.w = s.w + p.w;
  ((float4*)x)[idx] = o;
}

// ---------------------------------------------------------------- generic GEMM
// C[M,N] = A[M,K] @ W[N,K]^T + bias, f32. 64x64 tile, BK=16, 256 thr, 4x4/thr.
// flags: RELU, ADD (C += result), KVH (store bf16 head-major [B,NH,T,64] to Cb)
__global__ __launch_bounds__(256) void gemm_f32(
    const float* __restrict__ A, const float* __restrict__ W,
    const float* __restrict__ bias, float* __restrict__ C,
    __hip_bfloat16* __restrict__ Cb, int M, int N, int K, int flags) {
  __shared__ float As[16][65];
  __shared__ float Ws[16][65];
  int t = threadIdx.x;
  int tx = t & 15, ty = t >> 4;
  int bm = blockIdx.y * 64, bn = blockIdx.x * 64;
  int lr = t >> 2, lk = (t & 3) * 4;
  float acc[4][4] = {};
  const float* Arow = A + (size_t)(bm + lr) * K + lk;
  const float* Wrow = W + (size_t)(bn + lr) * K + lk;
  for (int k0 = 0; k0 < K; k0 += 16) {
    float4 av = *(const float4*)(Arow + k0);
    float4 wv = *(const float4*)(Wrow + k0);
    __syncthreads();
    As[lk + 0][lr] = av.x; As[lk + 1][lr] = av.y; As[lk + 2][lr] = av.z; As[lk + 3][lr] = av.w;
    Ws[lk + 0][lr] = wv.x; Ws[lk + 1][lr] = wv.y; Ws[lk + 2][lr] = wv.z; Ws[lk + 3][lr] = wv.w;
    __syncthreads();
#pragma unroll
    for (int k = 0; k < 16; ++k) {
      float a[4], w[4];
#pragma unroll
      for (int i = 0; i < 4; ++i) a[i] = As[k][ty * 4 + i];
#pragma unroll
      for (int j = 0; j < 4; ++j) w[j] = Ws[k][tx * 4 + j];
#pragma unroll
      for (int i = 0; i < 4; ++i)
#pragma unroll
        for (int j = 0; j < 4; ++j) acc[i][j] += a[i] * w[j];
    }
  }
#pragma unroll
  for (int i = 0; i < 4; ++i) {
    int row = bm + ty * 4 + i;
#pragma unroll
    for (int j = 0; j < 4; ++j) {
      int col = bn + tx * 4 + j;
      float v = acc[i][j];
      if (bias) v += bias[col];
      if (flags & GF_ADD) v += C[(size_t)row * N + col];
      if (flags & GF_RELU) v = fmaxf(v, 0.f);
      if (flags & GF_KVH) {
        int b = row >> 9, kk = row & 511;   // T_=512
        int n = col >> 6, d = col & 63;     // dh=64
        Cb[(((size_t)(b * 4 + n) * 512) + kk) * 64 + d] = __float2bfloat16(v);
      } else {
        C[(size_t)row * N + col] = v;
      }
    }
  }
}

// ---------------------------------------------------------------- GRU step
// One launch = one time step, both directions. grid (4, 16, 2); 64x64 h tile,
// 3 gate GEMM tiles fused + gate math + write h_new and outputs slab.
__global__ __launch_bounds__(256) void gru_step(
    const float* __restrict__ xg_f, const float* __restrict__ xg_b,
    const float* __restrict__ whh_f, const float* __restrict__ bhh_f,
    const float* __restrict__ whh_b, const float* __restrict__ bhh_b,
    const float* __restrict__ h_in, float* __restrict__ h_out,
    float* __restrict__ outputs, int s) {
  __shared__ float hs[16][65];
  __shared__ float ws[3][16][65];
  int dir = blockIdx.z;
  int bm = blockIdx.y * 64, bn = blockIdx.x * 64;
  const float* xg = dir ? xg_b : xg_f;
  const float* W = dir ? whh_b : whh_f;
  const float* bhh = dir ? bhh_b : bhh_f;
  int sd = dir ? (S_ - 1 - s) : s;
  const float* hi = h_in + (size_t)dir * B_ * H_;
  int t = threadIdx.x;
  int tx = t & 15, ty = t >> 4;
  int lr = t >> 2, lk = (t & 3) * 4;
  float ar[4][4] = {}, az[4][4] = {}, an[4][4] = {};
  for (int k0 = 0; k0 < 256; k0 += 16) {
    float4 hv = *(const float4*)&hi[(size_t)(bm + lr) * 256 + k0 + lk];
    float4 w0 = *(const float4*)&W[(size_t)(bn + lr) * 256 + k0 + lk];
    float4 w1 = *(const float4*)&W[(size_t)(256 + bn + lr) * 256 + k0 + lk];
    float4 w2 = *(const float4*)&W[(size_t)(512 + bn + lr) * 256 + k0 + lk];
    __syncthreads();
    hs[lk + 0][lr] = hv.x; hs[lk + 1][lr] = hv.y; hs[lk + 2][lr] = hv.z; hs[lk + 3][lr] = hv.w;
    ws[0][lk + 0][lr] = w0.x; ws[0][lk + 1][lr] = w0.y; ws[0][lk + 2][lr] = w0.z; ws[0][lk + 3][lr] = w0.w;
    ws[1][lk + 0][lr] = w1.x; ws[1][lk + 1][lr] = w1.y; ws[1][lk + 2][lr] = w1.z; ws[1][lk + 3][lr] = w1.w;
    ws[2][lk + 0][lr] = w2.x; ws[2][lk + 1][lr] = w2.y; ws[2][lk + 2][lr] = w2.z; ws[2][lk + 3][lr] = w2.w;
    __syncthreads();
#pragma unroll
    for (int k = 0; k < 16; ++k) {
      float a[4], gr[4], gz[4], gn[4];
#pragma unroll
      for (int i = 0; i < 4; ++i) a[i] = hs[k][ty * 4 + i];
#pragma unroll
      for (int j = 0; j < 4; ++j) {
        gr[j] = ws[0][k][tx * 4 + j];
        gz[j] = ws[1][k][tx * 4 + j];
        gn[j] = ws[2][k][tx * 4 + j];
      }
#pragma unroll
      for (int i = 0; i < 4; ++i)
#pragma unroll
        for (int j = 0; j < 4; ++j) {
          ar[i][j] += a[i] * gr[j];
          az[i][j] += a[i] * gz[j];
          an[i][j] += a[i] * gn[j];
        }
    }
  }
#pragma unroll
  for (int i = 0; i < 4; ++i) {
    int bg = bm + ty * 4 + i;
#pragma unroll
    for (int j = 0; j < 4; ++j) {
      int ig = bn + tx * 4 + j;
      size_t xbase = ((size_t)bg * S_ + sd) * 768 + ig;
      float xr = xg[xbase], xz = xg[xbase + 256], xn = xg[xbase + 512];
      float hr = ar[i][j] + bhh[ig];
      float hz = az[i][j] + bhh[256 + ig];
      float hn = an[i][j] + bhh[512 + ig];
      float r = sigmoidf_(xr + hr);
      float z = sigmoidf_(xz + hz);
      float n = tanhf(xn + r * hn);
      float ho = hi[(size_t)bg * 256 + ig];
      float hnew = (1.f - z) * n + z * ho;
      h_out[(size_t)dir * B_ * H_ + (size_t)bg * 256 + ig] = hnew;
      outputs[((size_t)bg * S_ + sd) * 512 + dir * 256 + ig] = hnew;
    }
  }
}

// ---------------------------------------------------------------- self attention
// One block per (b, head). S=50, dh=128. Everything in LDS, f32.
__global__ __launch_bounds__(256) void self_attn(const float* __restrict__ qkv,
                                                 float* __restrict__ ctx) {
  __shared__ float Qs[50][129];
  __shared__ float KVs[50][129];
  __shared__ float Ss[50][52];
  int bn = blockIdx.x;
  int b = bn >> 2, n = bn & 3;
  int t = threadIdx.x;
  const float scale = 0.08838834764831845f;  // 1/sqrt(128)
  for (int idx = t; idx < 6400; idx += 256) {
    int q = idx >> 7, d = idx & 127;
    size_t base = ((size_t)b * S_ + q) * 1536 + n * 128 + d;
    Qs[q][d] = qkv[base] * scale;
    KVs[q][d] = qkv[base + 512];
  }
  __syncthreads();
  for (int o = t; o < 2500; o += 256) {
    int q = o / 50, k = o % 50;
    float acc = 0.f;
#pragma unroll 8
    for (int d = 0; d < 128; ++d) acc += Qs[q][d] * KVs[k][d];
    Ss[q][k] = acc;
  }
  __syncthreads();
  int lane = t & 63, w = t >> 6;
  for (int q = w; q < 50; q += 4) {
    float v = lane < 50 ? Ss[q][lane] : -1e30f;
    float m = v;
#pragma unroll
    for (int off = 32; off; off >>= 1) m = fmaxf(m, __shfl_xor(m, off));
    float e = lane < 50 ? __expf(v - m) : 0.f;
    float sum = e;
#pragma unroll
    for (int off = 32; off; off >>= 1) sum += __shfl_xor(sum, off);
    if (lane < 50) Ss[q][lane] = e / sum;
  }
  __syncthreads();
  for (int idx = t; idx < 6400; idx += 256) {
    int q = idx >> 7, d = idx & 127;
    KVs[q][d] = qkv[((size_t)b * S_ + q) * 1536 + 1024 + n * 128 + d];
  }
  __syncthreads();
  for (int o = t; o < 6400; o += 256) {
    int q = o >> 7, d = o & 127;
    float a = 0.f;
#pragma unroll
    for (int k = 0; k < 50; ++k) a += Ss[q][k] * KVs[k][d];
    ctx[((size_t)b * S_ + q) * 512 + n * 128 + d] = a;
  }
}

// ---------------------------------------------------------------- cross attention
// One block per (b, head). S=50 queries, T=512 keys, dh=64. K/V bf16 head-major.
__global__ __launch_bounds__(256) void cross_attn(
    const float* __restrict__ q2, const __hip_bfloat16* __restrict__ K2,
    const __hip_bfloat16* __restrict__ V2, float* __restrict__ ctx2) {
  __shared__ float Qs[50][65];
  __shared__ float Ss[50][513];
  __shared__ float Kt[64][67];
  int bn = blockIdx.x;
  int b = bn >> 2, n = bn & 3;
  int t = threadIdx.x;
  const float scale = 0.125f;  // 1/sqrt(64)
  for (int idx = t; idx < 3200; idx += 256) {
    int q = idx >> 6, d = idx & 63;
    Qs[q][d] = q2[((size_t)b * S_ + q) * 256 + n * 64 + d] * scale;
  }
  const __hip_bfloat16* Kh = K2 + (size_t)bn * T_ * 64;
  const __hip_bfloat16* Vh = V2 + (size_t)bn * T_ * 64;
  for (int kt = 0; kt < 8; ++kt) {
    __syncthreads();
    for (int idx = t; idx < 4096; idx += 256) {
      int r = idx >> 6, d = idx & 63;
      Kt[r][d] = __bfloat162float(Kh[(size_t)(kt * 64 + r) * 64 + d]);
    }
    __syncthreads();
    for (int o = t; o < 3200; o += 256) {
      int q = o >> 6, r = o & 63;
      float acc = 0.f;
#pragma unroll 8
      for (int d = 0; d < 64; ++d) acc += Qs[q][d] * Kt[r][d];
      Ss[q][kt * 64 + r] = acc;
    }
  }
  __syncthreads();
  int lane = t & 63, w = t >> 6;
  for (int q = w; q < 50; q += 4) {
    float m = -1e30f;
#pragma unroll
    for (int i = 0; i < 8; ++i) m = fmaxf(m, Ss[q][lane + i * 64]);
#pragma unroll
    for (int off = 32; off; off >>= 1) m = fmaxf(m, __shfl_xor(m, off));
    float sum = 0.f;
#pragma unroll
    for (int i = 0; i < 8; ++i) {
      float e = __expf(Ss[q][lane + i * 64] - m);
      Ss[q][lane + i * 64] = e;
      sum += e;
    }
#pragma unroll
    for (int off = 32; off; off >>= 1) sum += __shfl_xor(sum, off);
    float inv = 1.f / sum;
#pragma unroll
    for (int i = 0; i < 8; ++i) Ss[q][lane + i * 64] *= inv;
  }
  float acc[13];
#pragma unroll
  for (int i = 0; i < 13; ++i) acc[i] = 0.f;
  for (int vt = 0; vt < 8; ++vt) {
    __syncthreads();
    for (int idx = t; idx < 4096; idx += 256) {
      int r = idx >> 6, d = idx & 63;
      Kt[r][d] = __bfloat162float(Vh[(size_t)(vt * 64 + r) * 64 + d]);
    }
    __syncthreads();
#pragma unroll
    for (int i = 0; i < 13; ++i) {
      int o = t + i * 256;
      if (o < 3200) {
        int q = o >> 6, d = o & 63;
        float a = acc[i];
#pragma unroll 8
        for (int r = 0; r < 64; ++r) a += Ss[q][vt * 64 + r] * Kt[r][d];
        acc[i] = a;
      }
    }
  }
#pragma unroll
  for (int i = 0; i < 13; ++i) {
    int o = t + i * 256;
    if (o < 3200) {
      int q = o >> 6, d = o & 63;
      ctx2[((size_t)b * S_ + q) * 256 + n * 64 + d] = acc[i];
    }
  }
}

// ---------------------------------------------------------------- LayerNorm
// Y = LN(X [+ R]) * g + b, optional relu. One wave per row.
template <int LL>
__global__ __launch_bounds__(256) void ln_kernel(
    const float* __restrict__ X, const float* __restrict__ R,
    const float* __restrict__ g, const float* __restrict__ bta,
    float* __restrict__ Y, int relu) {
  constexpr int NV = LL / 64;
  int row = blockIdx.x * 4 + (threadIdx.x >> 6);
  int lane = threadIdx.x & 63;
  const float* xr = X + (size_t)row * LL;
  float vals[NV];
  float s1 = 0.f, s2 = 0.f;
#pragma unroll
  for (int i = 0; i < NV; ++i) {
    int c = lane + (i << 6);
    float v = xr[c];
    if (R) v += R[(size_t)row * LL + c];
    vals[i] = v;
    s1 += v;
    s2 += v * v;
  }
#pragma unroll
  for (int off = 32; off; off >>= 1) {
    s1 += __shfl_xor(s1, off);
    s2 += __shfl_xor(s2, off);
  }
  float m = s1 * (1.f / LL);
  float var = s2 * (1.f / LL) - m * m;
  float rstd = rsqrtf(var + 1e-5f);
#pragma unroll
  for (int i = 0; i < NV; ++i) {
    int c = lane + (i << 6);
    float y = (vals[i] - m) * rstd * g[c] + bta[c];
    if (relu) y = fmaxf(y, 0.f);
    Y[(size_t)row * LL + c] = y;
  }
}

// ---------------------------------------------------------------- final head
__global__ __launch_bounds__(256) void cls_kernel(const float* __restrict__ E,
                                                  const float* __restrict__ cw,
                                                  const float* __restrict__ cb,
                                                  float* __restrict__ out) {
  int row = blockIdx.x * 4 + (threadIdx.x >> 6);
  int lane = threadIdx.x & 63;
  float4 e = *(const float4*)&E[(size_t)row * 256 + lane * 4];
  float4 w0 = *(const float4*)&cw[lane * 4];
  float4 w1 = *(const float4*)&cw[256 + lane * 4];
  float a0 = e.x * w0.x + e.y * w0.y + e.z * w0.z + e.w * w0.w;
  float a1 = e.x * w1.x + e.y * w1.y + e.z * w1.z + e.w * w1.w;
#pragma unroll
  for (int off = 32; off; off >>= 1) {
    a0 += __shfl_xor(a0, off);
    a1 += __shfl_xor(a1, off);
  }
  if (lane == 0) {
    out[(size_t)row * 2 + 0] = a0 + cb[0];
    out[(size_t)row * 2 + 1] = a1 + cb[1];
  }
}

// ================================================================ launch
extern "C" void kernel_launch(void* const* d_in, const int* in_sizes, int n_in,
                              void* d_out, int out_size, void* d_ws, size_t ws_size,
                              hipStream_t stream) {
  (void)in_sizes; (void)n_in; (void)out_size;
  const float* syl      = (const float*)d_in[0];
  const float* phon     = (const float*)d_in[1];
  const float* enc      = (const float*)d_in[2];
  const float* pos      = (const float*)d_in[3];
  const float* wih_f    = (const float*)d_in[4];
  const float* whh_f    = (const float*)d_in[5];
  const float* bih_f    = (const float*)d_in[6];
  const float* bhh_f    = (const float*)d_in[7];
  const float* wih_b    = (const float*)d_in[8];
  const float* whh_b    = (const float*)d_in[9];
  const float* bih_b    = (const float*)d_in[10];
  const float* bhh_b    = (const float*)d_in[11];
  const float* tf_in_w  = (const float*)d_in[12];
  const float* tf_in_b  = (const float*)d_in[13];
  const float* tf_out_w = (const float*)d_in[14];
  const float* tf_out_b = (const float*)d_in[15];
  const float* lin1_w   = (const float*)d_in[16];
  const float* lin1_b   = (const float*)d_in[17];
  const float* lin2_w   = (const float*)d_in[18];
  const float* lin2_b   = (const float*)d_in[19];
  const float* ln1_g    = (const float*)d_in[20];
  const float* ln1_b    = (const float*)d_in[21];
  const float* ln2_g    = (const float*)d_in[22];
  const float* ln2_b    = (const float*)d_in[23];
  const float* sc_w     = (const float*)d_in[24];
  const float* sc_b     = (const float*)d_in[25];
  const float* scln_g   = (const float*)d_in[26];
  const float* scln_b   = (const float*)d_in[27];
  const float* pp_w     = (const float*)d_in[28];
  const float* pp_b     = (const float*)d_in[29];
  const float* mha_in_w = (const float*)d_in[30];
  const float* mha_in_b = (const float*)d_in[31];
  const float* mha_out_w= (const float*)d_in[32];
  const float* mha_out_b= (const float*)d_in[33];
  const float* cls_w    = (const float*)d_in[34];
  const float* cls_b    = (const float*)d_in[35];

  const size_t NEED = 799014912ULL;  // 199,753,728 f32
  if (ws_size < NEED) {
    fprintf(stderr, "[StressDecoder kernel] ws too small: %zu < %zu\n",
            ws_size, NEED);
    return;
  }

  float* ws = (float*)d_ws;
  float* outputs = ws;                    // [BS,512] — GRU out, later y, later tf_out
  float* pool = ws + 26214400;
  // phase 1 (GRU)
  float* x    = pool;                     // [BS,256]
  float* xg_f = pool + 13107200;          // [BS,768] laid out [B,S,768]
  float* xg_b = pool + 52428800;          // [BS,768]
  float* hbuf = pool + 91750400;          // 2 ping-pong x 2 dirs x [B,H]
  // phase 2 (self-attn)
  float* qkv  = pool;                     // [BS,1536]
  float* ctxb = pool + 78643200;          // [BS,512]
  float* aproj= pool;                     // [BS,512] (qkv dead by then)
  // phase 3 (FF)
  float* ff1  = pool;                     // [BS,2048]
  float* ff2  = pool + 104857600;         // [BS,512]
  // phase 4 (syllable context)
  float* sc_pre = pool;                   // [BS,256]
  float* scb    = pool + 13107200;        // [BS,256] — sc, later enhanced
  // phase 5 (cross-attn)
  float* q2   = pool + 26214400;          // [BS,256]
  __hip_bfloat16* K2 = (__hip_bfloat16*)(pool + 39321600);   // [B,4,512,64] bf16
  __hip_bfloat16* V2 = (__hip_bfloat16*)(pool + 106430464);  // [B,4,512,64] bf16
  float* ctx2 = pool;                     // [BS,256] (sc_pre dead)

  hipMemsetAsync(hbuf, 0, (size_t)2 * B_ * H_ * sizeof(float), stream);
  add_pos<<<12800, 256, 0, stream>>>(syl, pos, x);
  gemm_f32<<<dim3(12, 800), 256, 0, stream>>>(x, wih_f, bih_f, xg_f, nullptr, BS_, 768, 256, 0);
  gemm_f32<<<dim3(12, 800), 256, 0, stream>>>(x, wih_b, bih_b, xg_b, nullptr, BS_, 768, 256, 0);

  float* hA = hbuf;
  float* hB = hbuf + 524288;
  for (int s = 0; s < S_; ++s) {
    gru_step<<<dim3(4, 16, 2), 256, 0, stream>>>(xg_f, xg_b, whh_f, bhh_f,
                                                 whh_b, bhh_b, hA, hB, outputs, s);
    float* tmp = hA; hA = hB; hB = tmp;
  }

  gemm_f32<<<dim3(24, 800), 256, 0, stream>>>(outputs, tf_in_w, tf_in_b, qkv, nullptr, BS_, 1536, 512, 0);
  self_attn<<<4096, 256, 0, stream>>>(qkv, ctxb);
  gemm_f32<<<dim3(8, 800), 256, 0, stream>>>(ctxb, tf_out_w, tf_out_b, aproj, nullptr, BS_, 512, 512, 0);
  ln_kernel<512><<<12800, 256, 0, stream>>>(outputs, aproj, ln1_g, ln1_b, outputs, 0);
  gemm_f32<<<dim3(32, 800), 256, 0, stream>>>(outputs, lin1_w, lin1_b, ff1, nullptr, BS_, 2048, 512, GF_RELU);
  gemm_f32<<<dim3(8, 800), 256, 0, stream>>>(ff1, lin2_w, lin2_b, ff2, nullptr, BS_, 512, 2048, 0);
  ln_kernel<512><<<12800, 256, 0, stream>>>(outputs, ff2, ln2_g, ln2_b, outputs, 0);
  gemm_f32<<<dim3(4, 800), 256, 0, stream>>>(outputs, sc_w, sc_b, sc_pre, nullptr, BS_, 256, 512, 0);
  ln_kernel<256><<<12800, 256, 0, stream>>>(sc_pre, nullptr, scln_g, scln_b, scb, 1);
  gemm_f32<<<dim3(4, 800), 256, 0, stream>>>(phon, pp_w, pp_b, scb, nullptr, BS_, 256, 256, GF_ADD);
  gemm_f32<<<dim3(4, 800), 256, 0, stream>>>(scb, mha_in_w, mha_in_b, q2, nullptr, BS_, 256, 256, 0);
  gemm_f32<<<dim3(4, 8192), 256, 0, stream>>>(enc, mha_in_w + 65536, mha_in_b + 256, nullptr, K2, BT_, 256, 256, GF_KVH);
  gemm_f32<<<dim3(4, 8192), 256, 0, stream>>>(enc, mha_in_w + 131072, mha_in_b + 512, nullptr, V2, BT_, 256, 256, GF_KVH);
  cross_attn<<<4096, 256, 0, stream>>>(q2, K2, V2, ctx2);
  gemm_f32<<<dim3(4, 800), 256, 0, stream>>>(ctx2, mha_out_w, mha_out_b, scb, nullptr, BS_, 256, 256, GF_ADD);
  cls_kernel<<<12800, 256, 0, stream>>>(scb, cls_w, cls_b, (float*)d_out);
}

// Round 2
// 5561.880 us; speedup vs baseline: 3.3104x; 3.3104x over previous
//
#include <hip/hip_runtime.h>
#include <hip/hip_bf16.h>
#include <cstdio>
#include <cstddef>

#define B_ 1024
#define S_ 50
#define H_ 256
#define T_ 512
#define D_ 512
#define DFF_ 2048
#define BS_ 51200
#define BT_ 524288

enum { GF_RELU = 1, GF_ADD = 2, GF_KVH = 4, GF_ONLYB = 8 };

typedef __bf16 bf16x8 __attribute__((ext_vector_type(8)));
typedef float f32x4 __attribute__((ext_vector_type(4)));

__device__ __forceinline__ float sigmoidf_(float v) {
  return 1.f / (1.f + __expf(-v));
}
__device__ __forceinline__ unsigned short bfbits(float x) {
  return __bfloat16_as_ushort(__float2bfloat16(x));
}
__device__ __forceinline__ unsigned pk2(float a, float b) {
  return ((unsigned)bfbits(b) << 16) | (unsigned)bfbits(a);
}

#define GLDS16(g, l)                                                         \
  __builtin_amdgcn_global_load_lds(                                          \
      (const __attribute__((address_space(1))) void*)(g),                    \
      (__attribute__((address_space(3))) void*)(l), 16, 0, 0)

// ---------------------------------------------------------------- add pos emb
__global__ __launch_bounds__(256) void add_pos(const float* __restrict__ syl,
                                               const float* __restrict__ pos,
                                               __hip_bfloat16* __restrict__ x) {
  int idx = blockIdx.x * 256 + threadIdx.x;  // float4 index
  if (idx >= 3276800) return;
  float4 s = ((const float4*)syl)[idx];
  int e0 = idx * 4;
  int h = e0 & 255;
  int sp = (e0 >> 8) % S_;
  float4 p = *(const float4*)&pos[sp * H_ + h];
  uint2 o;
  o.x = pk2(s.x + p.x, s.y + p.y);
  o.y = pk2(s.z + p.z, s.w + p.w);
  ((uint2*)x)[idx] = o;
}

// ---------------------------------------------------------------- casts
__global__ __launch_bounds__(256) void cast_f2b(const float* __restrict__ src,
                                                __hip_bfloat16* __restrict__ dst,
                                                int n4) {
  int g = blockIdx.x * 256 + threadIdx.x;
  if (g >= n4) return;
  float4 v = ((const float4*)src)[g];
  uint2 o;
  o.x = pk2(v.x, v.y);
  o.y = pk2(v.z, v.w);
  ((uint2*)dst)[g] = o;
}

__global__ __launch_bounds__(256) void cast_weights(
    const float* s0, const float* s1, const float* s2, const float* s3,
    const float* s4, const float* s5, const float* s6, const float* s7,
    const float* s8, const float* s9, __hip_bfloat16* __restrict__ dst) {
  int g = blockIdx.x * 256 + threadIdx.x;  // float4 idx
  if (g >= 999424) return;
  const float* s;
  int base;
  if      (g < 49152)  { s = s0; base = 0; }
  else if (g < 98304)  { s = s1; base = 49152; }
  else if (g < 294912) { s = s2; base = 98304; }
  else if (g < 360448) { s = s3; base = 294912; }
  else if (g < 622592) { s = s4; base = 360448; }
  else if (g < 884736) { s = s5; base = 622592; }
  else if (g < 917504) { s = s6; base = 884736; }
  else if (g < 933888) { s = s7; base = 917504; }
  else if (g < 983040) { s = s8; base = 933888; }
  else                 { s = s9; base = 983040; }
  float4 v = ((const float4*)s)[g - base];
  uint2 o;
  o.x = pk2(v.x, v.y);
  o.y = pk2(v.z, v.w);
  ((uint2*)dst)[g] = o;
}

// ---------------------------------------------------------------- MFMA GEMM
// C[M,N] = A[M,K](bf16) @ W[N,K](bf16)^T + bias. 128x128 tile, BK=64, 4 waves.
// LDS XOR-swizzle (T2) via pre-swizzled global source (rule #21).
__global__ __launch_bounds__(256) void gemm_bf16(
    const __hip_bfloat16* __restrict__ A, const __hip_bfloat16* __restrict__ W,
    const float* __restrict__ bias, float* __restrict__ C,
    __hip_bfloat16* __restrict__ Cb, __hip_bfloat16* __restrict__ Vb,
    int M, int N, int K, int flags, int m_off) {
  __shared__ __hip_bfloat16 As[128 * 64];
  __shared__ __hip_bfloat16 Bs[128 * 64];
  int t = threadIdx.x;
  int w = t >> 6, lane = t & 63;
  int wr = w >> 1, wc = w & 1;
  int bm = blockIdx.y * 128, bn = blockIdx.x * 128;

  // staging: lane covers row (lane>>3) of each 8-row chunk, swizzled col
  int sxr = lane >> 3;
  int sxc = ((lane & 7) ^ sxr) * 8;
  const __hip_bfloat16* Ab = A + (size_t)(bm + w * 32 + sxr) * K + sxc;
  const __hip_bfloat16* Wb = W + (size_t)(bn + w * 32 + sxr) * K + sxc;
  __hip_bfloat16* Asl = &As[(w * 32) * 64];
  __hip_bfloat16* Bsl = &Bs[(w * 32) * 64];

  // fragment LDS element offsets (swizzled read)
  int fr = lane & 15, fq = lane >> 4;
  int col0 = ((fq * 8) + 0) ^ ((lane & 7) * 8);
  int col1 = ((fq * 8) + 32) ^ ((lane & 7) * 8);

  f32x4 acc[4][4];
#pragma unroll
  for (int i = 0; i < 4; ++i)
#pragma unroll
    for (int j = 0; j < 4; ++j) {
      f32x4 z = {0.f, 0.f, 0.f, 0.f};
      acc[i][j] = z;
    }

  for (int k0 = 0; k0 < K; k0 += 64) {
    __syncthreads();
#pragma unroll
    for (int c = 0; c < 4; ++c) {
      GLDS16(Ab + (size_t)(c * 8) * K + k0, Asl + (c * 8) * 64);
      GLDS16(Wb + (size_t)(c * 8) * K + k0, Bsl + (c * 8) * 64);
    }
    __syncthreads();
#pragma unroll
    for (int ks = 0; ks < 2; ++ks) {
      int kc = ks ? col1 : col0;
      bf16x8 af[4], bf[4];
#pragma unroll
      for (int i = 0; i < 4; ++i)
        af[i] = *(const bf16x8*)&As[(wr * 64 + i * 16 + fr) * 64 + kc];
#pragma unroll
      for (int j = 0; j < 4; ++j)
        bf[j] = *(const bf16x8*)&Bs[(wc * 64 + j * 16 + fr) * 64 + kc];
#pragma unroll
      for (int i = 0; i < 4; ++i)
#pragma unroll
        for (int j = 0; j < 4; ++j)
          acc[i][j] = __builtin_amdgcn_mfma_f32_16x16x32_bf16(af[i], bf[j],
                                                              acc[i][j], 0, 0, 0);
    }
  }

#pragma unroll
  for (int i = 0; i < 4; ++i) {
#pragma unroll
    for (int j = 0; j < 4; ++j) {
      int col = bn + wc * 64 + j * 16 + fr;
      float bv = bias ? bias[col] : 0.f;
#pragma unroll
      for (int r = 0; r < 4; ++r) {
        int row = bm + wr * 64 + i * 16 + fq * 4 + r;
        float v = acc[i][j][r] + bv;
        if (flags & GF_ADD) v += C[(size_t)row * N + col];
        if (flags & GF_RELU) v = fmaxf(v, 0.f);
        if (flags & GF_KVH) {
          int grow = m_off + row;
          int b = grow >> 9, tk = grow & 511;
          int c2 = col & 255;
          int hd = c2 >> 6, dd = c2 & 63;
          __hip_bfloat16* dst = (col < 256) ? Cb : Vb;
          dst[(((size_t)(b * 4 + hd) * 512) + tk) * 64 + dd] = __float2bfloat16(v);
        } else if (flags & GF_ONLYB) {
          Cb[(size_t)row * N + col] = __float2bfloat16(v);
        } else {
          C[(size_t)row * N + col] = v;
        }
      }
    }
  }
}

// ---------------------------------------------------------------- GRU step
__global__ __launch_bounds__(256) void gru_step(
    const float* __restrict__ xg_f, const float* __restrict__ xg_b,
    const float* __restrict__ whh_f, const float* __restrict__ bhh_f,
    const float* __restrict__ whh_b, const float* __restrict__ bhh_b,
    const float* __restrict__ h_in, float* __restrict__ h_out,
    float* __restrict__ outputs, __hip_bfloat16* __restrict__ outb, int s) {
  __shared__ float hs[16][65];
  __shared__ float ws[3][16][65];
  int dir = blockIdx.z;
  int bm = blockIdx.y * 64, bn = blockIdx.x * 64;
  const float* xg = dir ? xg_b : xg_f;
  const float* W = dir ? whh_b : whh_f;
  const float* bhh = dir ? bhh_b : bhh_f;
  int sd = dir ? (S_ - 1 - s) : s;
  const float* hi = h_in + (size_t)dir * B_ * H_;
  int t = threadIdx.x;
  int tx = t & 15, ty = t >> 4;
  int lr = t >> 2, lk = (t & 3) * 4;
  float ar[4][4] = {}, az[4][4] = {}, an[4][4] = {};
  for (int k0 = 0; k0 < 256; k0 += 16) {
    float4 hv = *(const float4*)&hi[(size_t)(bm + lr) * 256 + k0 + lk];
    float4 w0 = *(const float4*)&W[(size_t)(bn + lr) * 256 + k0 + lk];
    float4 w1 = *(const float4*)&W[(size_t)(256 + bn + lr) * 256 + k0 + lk];
    float4 w2 = *(const float4*)&W[(size_t)(512 + bn + lr) * 256 + k0 + lk];
    __syncthreads();
    hs[lk + 0][lr] = hv.x; hs[lk + 1][lr] = hv.y; hs[lk + 2][lr] = hv.z; hs[lk + 3][lr] = hv.w;
    ws[0][lk + 0][lr] = w0.x; ws[0][lk + 1][lr] = w0.y; ws[0][lk + 2][lr] = w0.z; ws[0][lk + 3][lr] = w0.w;
    ws[1][lk + 0][lr] = w1.x; ws[1][lk + 1][lr] = w1.y; ws[1][lk + 2][lr] = w1.z; ws[1][lk + 3][lr] = w1.w;
    ws[2][lk + 0][lr] = w2.x; ws[2][lk + 1][lr] = w2.y; ws[2][lk + 2][lr] = w2.z; ws[2][lk + 3][lr] = w2.w;
    __syncthreads();
#pragma unroll
    for (int k = 0; k < 16; ++k) {
      float a[4], gr[4], gz[4], gn[4];
#pragma unroll
      for (int i = 0; i < 4; ++i) a[i] = hs[k][ty * 4 + i];
#pragma unroll
      for (int j = 0; j < 4; ++j) {
        gr[j] = ws[0][k][tx * 4 + j];
        gz[j] = ws[1][k][tx * 4 + j];
        gn[j] = ws[2][k][tx * 4 + j];
      }
#pragma unroll
      for (int i = 0; i < 4; ++i)
#pragma unroll
        for (int j = 0; j < 4; ++j) {
          ar[i][j] += a[i] * gr[j];
          az[i][j] += a[i] * gz[j];
          an[i][j] += a[i] * gn[j];
        }
    }
  }
#pragma unroll
  for (int i = 0; i < 4; ++i) {
    int bg = bm + ty * 4 + i;
#pragma unroll
    for (int j = 0; j < 4; ++j) {
      int ig = bn + tx * 4 + j;
      size_t xbase = ((size_t)bg * S_ + sd) * 768 + ig;
      float xr = xg[xbase], xz = xg[xbase + 256], xn = xg[xbase + 512];
      float r = sigmoidf_(xr + ar[i][j] + bhh[ig]);
      float z = sigmoidf_(xz + az[i][j] + bhh[256 + ig]);
      float n = tanhf(xn + r * (an[i][j] + bhh[512 + ig]));
      float ho = hi[(size_t)bg * 256 + ig];
      float hnew = (1.f - z) * n + z * ho;
      h_out[(size_t)dir * B_ * H_ + (size_t)bg * 256 + ig] = hnew;
      size_t obase = ((size_t)bg * S_ + sd) * 512 + dir * 256 + ig;
      outputs[obase] = hnew;
      outb[obase] = __float2bfloat16(hnew);
    }
  }
}

// ---------------------------------------------------------------- self attention
__global__ __launch_bounds__(256) void self_attn(const float* __restrict__ qkv,
                                                 __hip_bfloat16* __restrict__ ctx) {
  __shared__ float Qs[50][129];
  __shared__ float KVs[50][129];
  __shared__ float Ss[50][52];
  int bn = blockIdx.x;
  int b = bn >> 2, n = bn & 3;
  int t = threadIdx.x;
  const float scale = 0.08838834764831845f;  // 1/sqrt(128)
  for (int idx = t; idx < 6400; idx += 256) {
    int q = idx >> 7, d = idx & 127;
    size_t base = ((size_t)b * S_ + q) * 1536 + n * 128 + d;
    Qs[q][d] = qkv[base] * scale;
    KVs[q][d] = qkv[base + 512];
  }
  __syncthreads();
  for (int o = t; o < 2500; o += 256) {
    int q = o / 50, k = o % 50;
    float acc = 0.f;
#pragma unroll 8
    for (int d = 0; d < 128; ++d) acc += Qs[q][d] * KVs[k][d];
    Ss[q][k] = acc;
  }
  __syncthreads();
  int lane = t & 63, w = t >> 6;
  for (int q = w; q < 50; q += 4) {
    float v = lane < 50 ? Ss[q][lane] : -1e30f;
    float m = v;
#pragma unroll
    for (int off = 32; off; off >>= 1) m = fmaxf(m, __shfl_xor(m, off));
    float e = lane < 50 ? __expf(v - m) : 0.f;
    float sum = e;
#pragma unroll
    for (int off = 32; off; off >>= 1) sum += __shfl_xor(sum, off);
    if (lane < 50) Ss[q][lane] = e / sum;
  }
  __syncthreads();
  for (int idx = t; idx < 6400; idx += 256) {
    int q = idx >> 7, d = idx & 127;
    KVs[q][d] = qkv[((size_t)b * S_ + q) * 1536 + 1024 + n * 128 + d];
  }
  __syncthreads();
  for (int o = t; o < 6400; o += 256) {
    int q = o >> 7, d = o & 127;
    float a = 0.f;
#pragma unroll
    for (int k = 0; k < 50; ++k) a += Ss[q][k] * KVs[k][d];
    ctx[((size_t)b * S_ + q) * 512 + n * 128 + d] = __float2bfloat16(a);
  }
}

// ---------------------------------------------------------------- cross attention
// flash-style, 4x4 register micro-tiles, 3x ~17KB LDS -> 3 blocks/CU
__global__ __launch_bounds__(256) void cross_attn(
    const __hip_bfloat16* __restrict__ q2, const __hip_bfloat16* __restrict__ K2,
    const __hip_bfloat16* __restrict__ V2, __hip_bfloat16* __restrict__ ctx2) {
  __shared__ float Qt[64][68];  // [d][q]
  __shared__ float KP[64][68];  // K as [d][t], then P as [t][q]
  __shared__ float Vs[64][68];  // [t][d]
  int bn = blockIdx.x;
  int b = bn >> 2, n = bn & 3;
  int t = threadIdx.x;
  int ty = t >> 4, tx = t & 15;
  for (int idx = t; idx < 4096; idx += 256) {
    int d = idx & 63, q = idx >> 6;
    float v = 0.f;
    if (q < 50) v = __bfloat162float(q2[((size_t)b * S_ + q) * 256 + n * 64 + d]) * 0.125f;
    Qt[d][q] = v;
  }
  const __hip_bfloat16* Kh = K2 + (size_t)bn * 512 * 64;
  const __hip_bfloat16* Vh = V2 + (size_t)bn * 512 * 64;
  float o[4][4] = {};
  float m[4], l[4];
#pragma unroll
  for (int i = 0; i < 4; ++i) { m[i] = -1e30f; l[i] = 0.f; }
  for (int kt = 0; kt < 8; ++kt) {
    __syncthreads();
    for (int idx = t; idx < 4096; idx += 256) {
      int d = idx & 63, r = idx >> 6;
      float kv = __bfloat162float(Kh[(size_t)(kt * 64 + r) * 64 + d]);
      float vv = __bfloat162float(Vh[(size_t)(kt * 64 + r) * 64 + d]);
      KP[d][r] = kv;
      Vs[r][d] = vv;
    }
    __syncthreads();
    float s[4][4] = {};
    for (int d = 0; d < 64; ++d) {
      f32x4 a = *(const f32x4*)&Qt[d][ty * 4];
      f32x4 bb = *(const f32x4*)&KP[d][tx * 4];
#pragma unroll
      for (int i = 0; i < 4; ++i)
#pragma unroll
        for (int j = 0; j < 4; ++j) s[i][j] += a[i] * bb[j];
    }
#pragma unroll
    for (int i = 0; i < 4; ++i) {
      float mt = fmaxf(fmaxf(s[i][0], s[i][1]), fmaxf(s[i][2], s[i][3]));
#pragma unroll
      for (int off = 8; off; off >>= 1) mt = fmaxf(mt, __shfl_xor(mt, off));
      float mn = fmaxf(m[i], mt);
      float c = __expf(m[i] - mn);
      float ps = 0.f;
#pragma unroll
      for (int j = 0; j < 4; ++j) {
        float p = __expf(s[i][j] - mn);
        s[i][j] = p;
        ps += p;
      }
#pragma unroll
      for (int off = 8; off; off >>= 1) ps += __shfl_xor(ps, off);
      l[i] = l[i] * c + ps;
      m[i] = mn;
#pragma unroll
      for (int j = 0; j < 4; ++j) o[i][j] *= c;
    }
    __syncthreads();
#pragma unroll
    for (int i = 0; i < 4; ++i)
#pragma unroll
      for (int j = 0; j < 4; ++j) KP[tx * 4 + j][ty * 4 + i] = s[i][j];
    __syncthreads();
    for (int tt = 0; tt < 64; ++tt) {
      f32x4 p = *(const f32x4*)&KP[tt][ty * 4];
      f32x4 vv = *(const f32x4*)&Vs[tt][tx * 4];
#pragma unroll
      for (int i = 0; i < 4; ++i)
#pragma unroll
        for (int j = 0; j < 4; ++j) o[i][j] += p[i] * vv[j];
    }
  }
#pragma unroll
  for (int i = 0; i < 4; ++i) {
    int q = ty * 4 + i;
    if (q >= 50) continue;
    float inv = 1.f / l[i];
#pragma unroll
    for (int j = 0; j < 4; ++j)
      ctx2[((size_t)b * S_ + q) * 256 + n * 64 + tx * 4 + j] =
          __float2bfloat16(o[i][j] * inv);
  }
}

// ---------------------------------------------------------------- LayerNorm
template <int LL>
__global__ __launch_bounds__(256) void ln_kernel(
    const float* __restrict__ X, const float* __restrict__ R,
    const float* __restrict__ g, const float* __restrict__ bta,
    float* __restrict__ Yf, __hip_bfloat16* __restrict__ Yb, int relu) {
  constexpr int NV = LL / 64;
  int row = blockIdx.x * 4 + (threadIdx.x >> 6);
  int lane = threadIdx.x & 63;
  const float* xr = X + (size_t)row * LL;
  float vals[NV];
  float s1 = 0.f, s2 = 0.f;
#pragma unroll
  for (int i = 0; i < NV; ++i) {
    int c = lane + (i << 6);
    float v = xr[c];
    if (R) v += R[(size_t)row * LL + c];
    vals[i] = v;
    s1 += v;
    s2 += v * v;
  }
#pragma unroll
  for (int off = 32; off; off >>= 1) {
    s1 += __shfl_xor(s1, off);
    s2 += __shfl_xor(s2, off);
  }
  float mn = s1 * (1.f / LL);
  float var = s2 * (1.f / LL) - mn * mn;
  float rstd = rsqrtf(var + 1e-5f);
#pragma unroll
  for (int i = 0; i < NV; ++i) {
    int c = lane + (i << 6);
    float y = (vals[i] - mn) * rstd * g[c] + bta[c];
    if (relu) y = fmaxf(y, 0.f);
    if (Yf) Yf[(size_t)row * LL + c] = y;
    if (Yb) Yb[(size_t)row * LL + c] = __float2bfloat16(y);
  }
}

// ---------------------------------------------------------------- final head
__global__ __launch_bounds__(256) void cls_kernel(const float* __restrict__ E,
                                                  const float* __restrict__ cw,
                                                  const float* __restrict__ cb,
                                                  float* __restrict__ out) {
  int row = blockIdx.x * 4 + (threadIdx.x >> 6);
  int lane = threadIdx.x & 63;
  float4 e = *(const float4*)&E[(size_t)row * 256 + lane * 4];
  float4 w0 = *(const float4*)&cw[lane * 4];
  float4 w1 = *(const float4*)&cw[256 + lane * 4];
  float a0 = e.x * w0.x + e.y * w0.y + e.z * w0.z + e.w * w0.w;
  float a1 = e.x * w1.x + e.y * w1.y + e.z * w1.z + e.w * w1.w;
#pragma unroll
  for (int off = 32; off; off >>= 1) {
    a0 += __shfl_xor(a0, off);
    a1 += __shfl_xor(a1, off);
  }
  if (lane == 0) {
    out[(size_t)row * 2 + 0] = a0 + cb[0];
    out[(size_t)row * 2 + 1] = a1 + cb[1];
  }
}

// ================================================================ launch
extern "C" void kernel_launch(void* const* d_in, const int* in_sizes, int n_in,
                              void* d_out, int out_size, void* d_ws, size_t ws_size,
                              hipStream_t stream) {
  (void)in_sizes; (void)n_in; (void)out_size;
  const float* syl      = (const float*)d_in[0];
  const float* phon     = (const float*)d_in[1];
  const float* enc      = (const float*)d_in[2];
  const float* pos      = (const float*)d_in[3];
  const float* wih_f    = (const float*)d_in[4];
  const float* whh_f    = (const float*)d_in[5];
  const float* bih_f    = (const float*)d_in[6];
  const float* bhh_f    = (const float*)d_in[7];
  const float* wih_b    = (const float*)d_in[8];
  const float* whh_b    = (const float*)d_in[9];
  const float* bih_b    = (const float*)d_in[10];
  const float* bhh_b    = (const float*)d_in[11];
  const float* tf_in_w  = (const float*)d_in[12];
  const float* tf_in_b  = (const float*)d_in[13];
  const float* tf_out_w = (const float*)d_in[14];
  const float* tf_out_b = (const float*)d_in[15];
  const float* lin1_w   = (const float*)d_in[16];
  const float* lin1_b   = (const float*)d_in[17];
  const float* lin2_w   = (const float*)d_in[18];
  const float* lin2_b   = (const float*)d_in[19];
  const float* ln1_g    = (const float*)d_in[20];
  const float* ln1_b    = (const float*)d_in[21];
  const float* ln2_g    = (const float*)d_in[22];
  const float* ln2_b    = (const float*)d_in[23];
  const float* sc_w     = (const float*)d_in[24];
  const float* sc_b     = (const float*)d_in[25];
  const float* scln_g   = (const float*)d_in[26];
  const float* scln_b   = (const float*)d_in[27];
  const float* pp_w     = (const float*)d_in[28];
  const float* pp_b     = (const float*)d_in[29];
  const float* mha_in_w = (const float*)d_in[30];
  const float* mha_in_b = (const float*)d_in[31];
  const float* mha_out_w= (const float*)d_in[32];
  const float* mha_out_b= (const float*)d_in[33];
  const float* cls_w    = (const float*)d_in[34];
  const float* cls_b    = (const float*)d_in[35];

  const size_t NEED = 785000000ULL;
  if (ws_size < NEED) {
    fprintf(stderr, "[StressDecoder kernel] ws too small: %zu < %zu\n",
            ws_size, NEED);
    return;
  }

  float* ws = (float*)d_ws;
  // Region A: outputs f32 (dead after ln2; reused for phon_b16 / enc chunks)
  float* outputs = ws;                                          // 26,214,400 f
  // Region B: bf16 activations (gru out -> y -> tf_out; then scb_b16+q2b)
  __hip_bfloat16* outb = (__hip_bfloat16*)(ws + 26214400);      // 26,214,400 bf16
  __hip_bfloat16* wpool = (__hip_bfloat16*)(ws + 39321600);     // 3,997,696 bf16
  float* hbuf = ws + 41320448;                                  // 1,048,576 f
  float* pool = ws + 42369024;

  __hip_bfloat16* wb_wihf  = wpool;
  __hip_bfloat16* wb_wihb  = wpool + 196608;
  __hip_bfloat16* wb_tfin  = wpool + 393216;
  __hip_bfloat16* wb_tfout = wpool + 1179648;
  __hip_bfloat16* wb_lin1  = wpool + 1441792;
  __hip_bfloat16* wb_lin2  = wpool + 2490368;
  __hip_bfloat16* wb_sc    = wpool + 3538944;
  __hip_bfloat16* wb_pp    = wpool + 3670016;
  __hip_bfloat16* wb_mhain = wpool + 3735552;
  __hip_bfloat16* wb_mhaout= wpool + 3932160;

  __hip_bfloat16* x_b16 = (__hip_bfloat16*)pool;        // 13.1M bf16
  float* xg_f = pool + 6553600;                         // 39.3M f
  float* xg_b = pool + 45875200;                        // 39.3M f
  float* qkv  = pool;                                   // 78.6M f
  __hip_bfloat16* ctxb = (__hip_bfloat16*)(pool + 78643200);  // 26.2M bf16
  float* aproj = pool + 91750400;                       // 26.2M f
  __hip_bfloat16* ff1b = (__hip_bfloat16*)pool;         // 104.9M bf16
  float* ff2 = pool + 52428800;                         // 26.2M f
  float* scb = pool;                                    // 13.1M f
  __hip_bfloat16* ctx2b = (__hip_bfloat16*)(pool + 13107200); // 13.1M bf16
  __hip_bfloat16* K2 = (__hip_bfloat16*)(pool + 19660800);    // 134.2M bf16
  __hip_bfloat16* V2 = (__hip_bfloat16*)(pool + 86769664);    // 134.2M bf16
  __hip_bfloat16* phonb = (__hip_bfloat16*)ws;          // region A reuse
  __hip_bfloat16* encb = (__hip_bfloat16*)ws;           // region A reuse
  __hip_bfloat16* scb_b16 = outb;                       // region B reuse
  __hip_bfloat16* q2b = outb + 6553600;                 // region B reuse

  cast_weights<<<3904, 256, 0, stream>>>(wih_f, wih_b, tf_in_w, tf_out_w,
                                         lin1_w, lin2_w, sc_w, pp_w,
                                         mha_in_w, mha_out_w, wpool);
  add_pos<<<12800, 256, 0, stream>>>(syl, pos, x_b16);
  gemm_bf16<<<dim3(6, 400), 256, 0, stream>>>(x_b16, wb_wihf, bih_f, xg_f,
                                              nullptr, nullptr, BS_, 768, 256, 0, 0);
  gemm_bf16<<<dim3(6, 400), 256, 0, stream>>>(x_b16, wb_wihb, bih_b, xg_b,
                                              nullptr, nullptr, BS_, 768, 256, 0, 0);

  hipMemsetAsync(hbuf, 0, (size_t)1048576 * sizeof(float), stream);
  float* hA = hbuf;
  float* hB = hbuf + 524288;
  for (int s = 0; s < S_; ++s) {
    gru_step<<<dim3(4, 16, 2), 256, 0, stream>>>(xg_f, xg_b, whh_f, bhh_f,
                                                 whh_b, bhh_b, hA, hB,
                                                 outputs, outb, s);
    float* tmp = hA; hA = hB; hB = tmp;
  }

  gemm_bf16<<<dim3(12, 400), 256, 0, stream>>>(outb, wb_tfin, tf_in_b, qkv,
                                               nullptr, nullptr, BS_, 1536, 512, 0, 0);
  self_attn<<<4096, 256, 0, stream>>>(qkv, ctxb);
  gemm_bf16<<<dim3(4, 400), 256, 0, stream>>>(ctxb, wb_tfout, tf_out_b, aproj,
                                              nullptr, nullptr, BS_, 512, 512, 0, 0);
  ln_kernel<512><<<12800, 256, 0, stream>>>(outputs, aproj, ln1_g, ln1_b,
                                            outputs, outb, 0);
  gemm_bf16<<<dim3(16, 400), 256, 0, stream>>>(outb, wb_lin1, lin1_b, nullptr,
                                               ff1b, nullptr, BS_, 2048, 512,
                                               GF_RELU | GF_ONLYB, 0);
  gemm_bf16<<<dim3(4, 400), 256, 0, stream>>>(ff1b, wb_lin2, lin2_b, ff2,
                                              nullptr, nullptr, BS_, 512, 2048, 0, 0);
  ln_kernel<512><<<12800, 256, 0, stream>>>(outputs, ff2, ln2_g, ln2_b,
                                            nullptr, outb, 0);
  gemm_bf16<<<dim3(2, 400), 256, 0, stream>>>(outb, wb_sc, sc_b, scb,
                                              nullptr, nullptr, BS_, 256, 512, 0, 0);
  ln_kernel<256><<<12800, 256, 0, stream>>>(scb, nullptr, scln_g, scln_b,
                                            scb, nullptr, 1);
  cast_f2b<<<12800, 256, 0, stream>>>(phon, phonb, 3276800);
  gemm_bf16<<<dim3(2, 400), 256, 0, stream>>>(phonb, wb_pp, pp_b, scb,
                                              nullptr, nullptr, BS_, 256, 256,
                                              GF_ADD, 0);
  cast_f2b<<<12800, 256, 0, stream>>>(scb, scb_b16, 3276800);
  gemm_bf16<<<dim3(2, 400), 256, 0, stream>>>(scb_b16, wb_mhain, mha_in_b,
                                              nullptr, q2b, nullptr, BS_, 256, 256,
                                              GF_ONLYB, 0);
  for (int ch = 0; ch < 4; ++ch) {
    const float* esrc = enc + (size_t)ch * 131072 * 256;
    cast_f2b<<<32768, 256, 0, stream>>>(esrc, encb, 8388608);
    gemm_bf16<<<dim3(4, 1024), 256, 0, stream>>>(encb, wb_mhain + 65536,
                                                 mha_in_b + 256, nullptr, K2, V2,
                                                 131072, 512, 256, GF_KVH,
                                                 ch * 131072);
  }
  cross_attn<<<4096, 256, 0, stream>>>(q2b, K2, V2, ctx2b);
  gemm_bf16<<<dim3(2, 400), 256, 0, stream>>>(ctx2b, wb_mhaout, mha_out_b, scb,
                                              nullptr, nullptr, BS_, 256, 256,
                                              GF_ADD, 0);
  cls_kernel<<<12800, 256, 0, stream>>>(scb, cls_w, cls_b, (float*)d_out);
}